// Round 7
// baseline (635.139 us; speedup 1.0000x reference)
//
#include <hip/hip_runtime.h>

typedef __attribute__((ext_vector_type(8))) short bfrag8;   // 8 bf16 = 4 VGPRs
typedef __attribute__((ext_vector_type(4))) float f32x4v;   // MFMA acc

__device__ inline short f2bf(float f) {
    unsigned u = __builtin_bit_cast(unsigned, f);
    u = (u + 0x7FFFu + ((u >> 16) & 1u)) >> 16;
    return (short)u;
}
__device__ inline float bf2f(short s) {
    unsigned u = ((unsigned)(unsigned short)s) << 16;
    return __builtin_bit_cast(float, u);
}
__device__ inline int pack2(short lo, short hi) {
    return (int)(((unsigned)(unsigned short)lo) | (((unsigned)(unsigned short)hi) << 16));
}

// ---------------- CSR construction ----------------

__global__ void deg_count_kernel(const int* __restrict__ dst, int E, int* __restrict__ deg) {
    int e = blockIdx.x * blockDim.x + threadIdx.x;
    if (e < E) atomicAdd(&deg[dst[e]], 1);
}

__global__ void block_sum_kernel(const int* __restrict__ deg, int n, int* __restrict__ bsums) {
    int i = blockIdx.x * 256 + threadIdx.x;
    int v = (i < n) ? deg[i] : 0;
#pragma unroll
    for (int off = 32; off > 0; off >>= 1) v += __shfl_down(v, off);
    __shared__ int wsum[4];
    int lane = threadIdx.x & 63, w = threadIdx.x >> 6;
    if (lane == 0) wsum[w] = v;
    __syncthreads();
    if (threadIdx.x == 0) bsums[blockIdx.x] = wsum[0] + wsum[1] + wsum[2] + wsum[3];
}

__global__ void scan_bsums_kernel(int* __restrict__ bsums, int B, int* __restrict__ offs, int n) {
    __shared__ int s[256];
    int tid = threadIdx.x;
    int v = (tid < B) ? bsums[tid] : 0;
    s[tid] = v;
    __syncthreads();
    for (int off = 1; off < 256; off <<= 1) {
        int t = (tid >= off) ? s[tid - off] : 0;
        __syncthreads();
        s[tid] += t;
        __syncthreads();
    }
    if (tid < B) bsums[tid] = (tid == 0) ? 0 : s[tid - 1];
    if (tid == 0) offs[n] = s[255];
}

__global__ void scan_final_kernel(const int* __restrict__ deg, int n,
                                  const int* __restrict__ bsums,
                                  int* __restrict__ offs, int* __restrict__ cursor,
                                  float* __restrict__ dinv) {
    __shared__ int s[256];
    int tid = threadIdx.x;
    int i = blockIdx.x * 256 + tid;
    int v = (i < n) ? deg[i] : 0;
    s[tid] = v;
    __syncthreads();
    for (int off = 1; off < 256; off <<= 1) {
        int t = (tid >= off) ? s[tid - off] : 0;
        __syncthreads();
        s[tid] += t;
        __syncthreads();
    }
    if (i < n) {
        int excl = s[tid] - v + bsums[blockIdx.x];
        offs[i] = excl;
        cursor[i] = excl;
        dinv[i] = rsqrtf((float)(v + 1));
    }
}

__global__ void csr_fill_kernel(const int* __restrict__ src, const int* __restrict__ dst, int E,
                                int* __restrict__ cursor, int* __restrict__ csr) {
    int e = blockIdx.x * blockDim.x + threadIdx.x;
    if (e < E) {
        int d = dst[e];
        int p = atomicAdd(&cursor[d], 1);
        csr[p] = src[e];
    }
}

// ---------------- fused weight transpose+bf16 for all 3 layers ----------------

__global__ void prep_w_kernel(const float* __restrict__ W1, short* __restrict__ Wt1,
                              const float* __restrict__ W2, short* __restrict__ Wt2,
                              const float* __restrict__ W3, short* __restrict__ Wt3) {
    int i = blockIdx.x * blockDim.x + threadIdx.x;
    if (i < 65536) {                       // W1: K=256, N=256
        int k = i >> 8, n = i & 255;
        Wt1[n * 256 + k] = f2bf(W1[i]);
    } else if (i < 65536 + 32768) {        // W2: K=256, N=128
        int j = i - 65536;
        int k = j >> 7, n = j & 127;
        Wt2[n * 256 + k] = f2bf(W2[j]);
    } else {                               // W3: K=128, N=128
        int j = i - 65536 - 32768;
        int k = j >> 7, n = j & 127;
        Wt3[n * 128 + k] = f2bf(W3[j]);
    }
}

// ---------------- x -> bf16 (8 elems/thread) ----------------

__global__ void x2b_kernel(const float* __restrict__ x, short* __restrict__ xb, int total8) {
    int i = blockIdx.x * blockDim.x + threadIdx.x;
    if (i < total8) {
        const float4* p = (const float4*)(x + (size_t)i * 8);
        float4 v0 = p[0], v1 = p[1];
        int4 w = make_int4(pack2(f2bf(v0.x), f2bf(v0.y)), pack2(f2bf(v0.z), f2bf(v0.w)),
                           pack2(f2bf(v1.x), f2bf(v1.y)), pack2(f2bf(v1.z), f2bf(v1.w)));
        *(int4*)(xb + (size_t)i * 8) = w;
    }
}

// ---------------- tall-skinny bf16 MFMA GEMM (unchanged from round 5) ----------------

template<int K>
__global__ __launch_bounds__(256, 2) void gemm_skinny_kernel(
        const short* __restrict__ A,     // [npad][K]
        const short* __restrict__ Bt,    // [N][K]
        const float* __restrict__ dinv,  // [npad]
        short* __restrict__ Tout, int ldt) {
    constexpr int BSTR = K + 8;
    __shared__ short Bs[64 * BSTR];

    const int tid = threadIdx.x;
    const int lane = tid & 63;
    const int wid = tid >> 6;
    const int l15 = lane & 15;
    const int quad = lane >> 4;
    const int q8 = quad * 8;
    const int bn = blockIdx.y * 64;
    const int row0 = blockIdx.x * 256 + wid * 64;

    {
        constexpr int TOT16 = 64 * K / 8;
#pragma unroll
        for (int i = tid; i < TOT16; i += 256) {
            int r = i / (K / 8);
            int c = (i % (K / 8)) * 8;
            *(int4*)&Bs[r * BSTR + c] = *(const int4*)&Bt[(size_t)(bn + r) * K + c];
        }
    }
    __syncthreads();

    f32x4v acc[4][4];
#pragma unroll
    for (int i = 0; i < 4; ++i)
#pragma unroll
        for (int j = 0; j < 4; ++j) acc[i][j] = (f32x4v){0.f, 0.f, 0.f, 0.f};

    const short* aBase = A + (size_t)(row0 + l15) * K + q8;

#pragma unroll
    for (int ks = 0; ks < K / 32; ++ks) {
        bfrag8 af[4], bf[4];
#pragma unroll
        for (int mt = 0; mt < 4; ++mt)
            af[mt] = *(const bfrag8*)(aBase + (size_t)mt * 16 * K + ks * 32);
#pragma unroll
        for (int nt = 0; nt < 4; ++nt)
            bf[nt] = *(const bfrag8*)&Bs[(nt * 16 + l15) * BSTR + ks * 32 + q8];
#pragma unroll
        for (int mt = 0; mt < 4; ++mt)
#pragma unroll
            for (int nt = 0; nt < 4; ++nt)
                acc[mt][nt] = __builtin_amdgcn_mfma_f32_16x16x32_bf16(af[mt], bf[nt], acc[mt][nt], 0, 0, 0);
    }

#pragma unroll
    for (int mt = 0; mt < 4; ++mt) {
#pragma unroll
        for (int r = 0; r < 4; ++r) {
            int grow = row0 + mt * 16 + quad * 4 + r;
            float di = dinv[grow];
            short* outp = Tout + (size_t)grow * ldt + bn + l15;
#pragma unroll
            for (int nt = 0; nt < 4; ++nt)
                outp[nt * 16] = f2bf(acc[mt][nt][r] * di);
        }
    }
}

// ---------------- XCD-sliced aggregation ----------------
// One wave per (node, 32-channel slice). slice = blockIdx.x % NSLICE so that,
// under round-robin block->XCD dispatch, each XCD's L2 only caches one
// 50176x64B slice of hn (3.2 MB < 4 MB L2) -> kills the 8x L2-miss
// amplification seen as FETCH_SIZE=189MB for a 25.7MB buffer.
// Lanes: eg=lane>>4 (4 edges in flight), cl=lane&15 (short2 = 2 channels).

template<int C, int NSLICE, bool WB>
__global__ __launch_bounds__(256) void agg_sliced_kernel(
        const short* __restrict__ hn, const float* __restrict__ dinv,
        const int* __restrict__ offs, const int* __restrict__ csr,
        const float* __restrict__ bias, float* __restrict__ out,
        short* __restrict__ hb, int coloff, int n) {
    const int wid = threadIdx.x >> 6;
    const int slice = blockIdx.x % NSLICE;
    const int node = (blockIdx.x / NSLICE) * 4 + wid;
    if (node >= n) return;
    const int lane = threadIdx.x & 63;
    const int eg = lane >> 4;         // edge group 0..3
    const int cl = lane & 15;         // channel pair index
    const int c0 = slice * 32 + cl * 2;
    const short* base = hn + c0;

    float ax = 0.f, ay = 0.f;
    int beg = offs[node], end = offs[node + 1];
    int e = beg;
    // 8 edges per round (2x unrolled over the 4 edge groups)
    for (; e + 8 <= end; e += 8) {
        int s0 = csr[e + eg];
        int s1 = csr[e + 4 + eg];
        short2 a = *(const short2*)(base + (size_t)s0 * C);
        short2 b = *(const short2*)(base + (size_t)s1 * C);
        ax += bf2f(a.x) + bf2f(b.x);
        ay += bf2f(a.y) + bf2f(b.y);
    }
    if (e + 4 <= end) {
        int s0 = csr[e + eg];
        short2 a = *(const short2*)(base + (size_t)s0 * C);
        ax += bf2f(a.x);
        ay += bf2f(a.y);
        e += 4;
    }
    int rem = end - e;                // 0..3
    if (eg < rem) {
        int s0 = csr[e + eg];
        short2 a = *(const short2*)(base + (size_t)s0 * C);
        ax += bf2f(a.x);
        ay += bf2f(a.y);
    }
    if (eg == 0) {                    // self loop
        short2 a = *(const short2*)(base + (size_t)node * C);
        ax += bf2f(a.x);
        ay += bf2f(a.y);
    }

    // reduce the 4 edge groups (lanes l, l^16, l^32, l^48)
    ax += __shfl_xor(ax, 16); ax += __shfl_xor(ax, 32);
    ay += __shfl_xor(ay, 16); ay += __shfl_xor(ay, 32);

    if (eg == 0) {
        float di = dinv[node];
        float rx = fmaxf(fmaf(di, ax, bias[c0 + 0]), 0.f);
        float ry = fmaxf(fmaf(di, ay, bias[c0 + 1]), 0.f);
        *(float2*)(out + (size_t)node * 512 + coloff + c0) = make_float2(rx, ry);
        if (WB)
            *(int*)(hb + (size_t)node * C + c0) = pack2(f2bf(rx), f2bf(ry));
    }
}

// ---------------- launch ----------------

extern "C" void kernel_launch(void* const* d_in, const int* in_sizes, int n_in,
                              void* d_out, int out_size, void* d_ws, size_t ws_size,
                              hipStream_t stream) {
    const float* x  = (const float*)d_in[0];
    const int*   ei = (const int*)d_in[1];
    const float* W1 = (const float*)d_in[2];
    const float* b1 = (const float*)d_in[3];
    const float* W2 = (const float*)d_in[4];
    const float* b2 = (const float*)d_in[5];
    const float* W3 = (const float*)d_in[6];
    const float* b3 = (const float*)d_in[7];

    const int IN_C = 256, H2 = 256, H1 = 128, OUT_C = 128;
    int n = in_sizes[0] / IN_C;   // 50000
    int E = in_sizes[1] / 2;      // 800000
    const int* src = ei;
    const int* dst = ei + E;

    int sb = (n + 255) / 256;     // 196
    int npad = sb * 256;          // 50176

    char* ws = (char*)d_ws;
    auto carve = [&](size_t bytes) { char* p = ws; ws += (bytes + 255) & ~(size_t)255; return p; };
    int*   deg    = (int*)  carve((size_t)n * 4);
    int*   offs   = (int*)  carve(((size_t)n + 1) * 4);
    int*   cursor = (int*)  carve((size_t)n * 4);
    float* dinv   = (float*)carve((size_t)npad * 4);
    int*   csr    = (int*)  carve((size_t)E * 4);
    int*   bsums  = (int*)  carve(256 * 4);
    short* Wt1    = (short*)carve((size_t)IN_C * H2 * 2);
    short* Wt2    = (short*)carve((size_t)H2 * H1 * 2);
    short* Wt3    = (short*)carve((size_t)H1 * OUT_C * 2);
    short* t      = (short*)carve((size_t)npad * 256 * 2);
    short* inb    = (short*)carve((size_t)npad * 256 * 2);  // xb -> h1b -> h2b

    float* out = (float*)d_out;
    int nblk = (n + 255) / 256;
    int ng4 = (n + 3) / 4;        // 12500 node groups of 4

    hipMemsetAsync(deg, 0, (size_t)n * sizeof(int), stream);
    deg_count_kernel<<<(E + 255) / 256, 256, 0, stream>>>(dst, E, deg);
    block_sum_kernel<<<nblk, 256, 0, stream>>>(deg, n, bsums);
    scan_bsums_kernel<<<1, 256, 0, stream>>>(bsums, nblk, offs, n);
    scan_final_kernel<<<nblk, 256, 0, stream>>>(deg, n, bsums, offs, cursor, dinv);
    csr_fill_kernel<<<(E + 255) / 256, 256, 0, stream>>>(src, dst, E, cursor, csr);

    prep_w_kernel<<<(65536 + 32768 + 16384 + 255) / 256, 256, 0, stream>>>(W1, Wt1, W2, Wt2, W3, Wt3);

    int total8 = n * IN_C / 8;
    x2b_kernel<<<(total8 + 255) / 256, 256, 0, stream>>>(x, inb, total8);

    // Layer 1
    gemm_skinny_kernel<256><<<dim3(sb, H2 / 64), 256, 0, stream>>>(inb, Wt1, dinv, t, H2);
    agg_sliced_kernel<256, 8, true><<<ng4 * 8, 256, 0, stream>>>(t, dinv, offs, csr, b1, out, inb, 0, n);

    // Layer 2 (K=256 -> C=128)
    gemm_skinny_kernel<256><<<dim3(sb, H1 / 64), 256, 0, stream>>>(inb, Wt2, dinv, t, H1);
    agg_sliced_kernel<128, 4, true><<<ng4 * 4, 256, 0, stream>>>(t, dinv, offs, csr, b2, out, inb, H2, n);

    // Layer 3 (K=128 -> C=128)
    gemm_skinny_kernel<128><<<dim3(sb, OUT_C / 64), 256, 0, stream>>>(inb, Wt3, dinv, t, OUT_C);
    agg_sliced_kernel<128, 4, false><<<ng4 * 4, 256, 0, stream>>>(t, dinv, offs, csr, b3, out, nullptr, H2 + H1, n);
}